// Round 5
// baseline (783.742 us; speedup 1.0000x reference)
//
#include <hip/hip_runtime.h>
#include <hip/hip_bf16.h>

// CouplingSplineLayer fused kernel for MI355X (gfx950), round 13.
// R13 = R8's proven phases (G1/G2/G3/epilogue arithmetic VERBATIM, 162 us
// champion) reorganized as a wave-specialized producer/consumer pipeline:
//  * 1024-thread blocks: waves 0-7 = GEMM (R8 mappings), waves 8-15 =
//    epilogue of the PREVIOUS tile. Each block loops 8 row-tiles + 1 drain.
//  * rawb is a SEPARATE LDS buffer (no h-alias): hbuf 66KB + rawb 66KB =
//    132 KB, 1 block/CU, 16 waves = 4/SIMD.
//  * Epilogue waves hoist raw->regs before S1, so their heavy VALU/TRANS
//    work (exp2/scan in S1-S2, softplus/spline/stores in S3-S5) overlaps
//    the GEMM waves' MFMA k-loops. Pipes that summed 33%+40% serially now
//    overlap.
//  * 4 uniform barriers/iter, all outside wave-role conditionals.
//  * Per-row traffic identical to R8 on every path; per-CU L2 weight
//    pressure halves (1 block streams weights instead of 2).

typedef __bf16 bf16x8 __attribute__((ext_vector_type(8)));
typedef __bf16 bf16x4v __attribute__((ext_vector_type(4)));
typedef float  f32x8 __attribute__((ext_vector_type(8)));
typedef float  f32x4 __attribute__((ext_vector_type(4)));
typedef float  f32x2 __attribute__((ext_vector_type(2)));

#define MFMA16(a,b,c) __builtin_amdgcn_mfma_f32_16x16x32_bf16((a),(b),(c),0,0,0)

#define SW_W1_OFF 8192      // W0: 1 kb * 16 tiles * 512
#define SW_WO_OFF 73728     // W1: 8 kb * 16 tiles * 512
#define SW_TOTAL  122880    // Wout': 8 kb * 12 tiles * 512 (192 padded cols)
// float bout'[192] lives at d_ws + SW_TOTAL*2 bytes

#define ROWS    128
#define IT      8           // row-tiles per block
#define HSTRIDE 264         // h row stride in bf16 (528 B: 16B-aligned)
#define LOG2E   1.44269504f
#define LN2     0.69314718f
#define SPCONST 0.7806568f      // log(exp(1-1e-4)-1) * log2e
#define ZSENT  (-0.00015680f)   // raw-z sentinel whose softplus-chain -> d = 1

__global__ void prep_kernel(const float* __restrict__ W0,
                            const float* __restrict__ W1,
                            const float* __restrict__ Wout,
                            const float* __restrict__ bout,
                            __bf16* __restrict__ sw)
{
  int i = blockIdx.x * 256 + threadIdx.x;
  if (i >= SW_TOTAL + 192) return;
  if (i >= SW_TOTAL){                      // bout'[192] remap (float, *log2e)
    int np = i - SW_TOTAL;
    int t = np / 24, p = np % 24;
    float* boutp = (float*)(sw + SW_TOTAL);
    boutp[np] = (p < 23) ? bout[t*23 + p] * LOG2E : 0.f;
    return;
  }
  const float* src; int K, N, NT, li;
  bool wo = false;
  if (i < SW_W1_OFF)      { src = W0;   K = 8;   N = 256; NT = 16; li = i; }
  else if (i < SW_WO_OFF) { src = W1;   K = 256; N = 256; NT = 16; li = i - SW_W1_OFF; }
  else { src = Wout; K = 256; N = 184; NT = 12; li = i - SW_WO_OFF; wo = true; }
  int j    = li & 7;
  int l    = (li >> 3) & 63;
  int rest = li >> 9;
  int nt   = rest % NT;
  int kb   = rest / NT;
  int k = kb * 32 + ((l >> 4) << 3) + j;
  int n = nt * 16 + (l & 15);
  float v;
  if (wo){
    int t = n / 24, p = n % 24;            // n is padded col n' in 0..191
    v = (p < 23 && k < K) ? Wout[k*184 + t*23 + p] * LOG2E : 0.f;
  } else {
    v = (k < K && n < N) ? src[k * N + n] : 0.f;
  }
  sw[i] = (__bf16)v;
}

__device__ __forceinline__ bf16x4v relu_cvt4(f32x4 acc, float4 bb){
  f32x4 s;
  s[0] = acc[0] + bb.x; s[1] = acc[1] + bb.y;
  s[2] = acc[2] + bb.z; s[3] = acc[3] + bb.w;
  f32x4 z = {0.f, 0.f, 0.f, 0.f};
  s = __builtin_elementwise_max(s, z);
  return __builtin_convertvector(s, bf16x4v);   // v_cvt_pk_bf16_f32 x2
}

__device__ __forceinline__ bf16x4v add_cvt4(f32x4 acc, float4 bb){
  f32x4 s;
  s[0] = acc[0] + bb.x; s[1] = acc[1] + bb.y;
  s[2] = acc[2] + bb.z; s[3] = acc[3] + bb.w;
  return __builtin_convertvector(s, bf16x4v);
}

__global__ __launch_bounds__(1024, 4)
void fused_kernel(const float* __restrict__ x,
                  const float* __restrict__ b0v,
                  const float* __restrict__ b1v,
                  const __bf16* __restrict__ sw,
                  float* __restrict__ out,
                  int nrows)
{
  // hbuf: h1 -> h2 (in place). rawb: separate (epilogue consumes prev tile).
  __shared__ __align__(16) unsigned char smemA[ROWS * HSTRIDE * 2];
  __shared__ __align__(16) unsigned char smemB[ROWS * HSTRIDE * 2];
  __bf16* hbuf = (__bf16*)smemA;
  __bf16* rawb = (__bf16*)smemB;

  const int tid  = threadIdx.x;
  const int wave = tid >> 6;          // 0..15
  const bool isW = wave < 8;          // GEMM waves
  const int lane = tid & 63;
  const int quad = lane >> 4;
  const int l16  = lane & 15;
  const int tid2 = tid - 512;         // epilogue-thread index [0,512)

  const __bf16* swW1 = sw + SW_W1_OFF;
  const __bf16* swWo = sw + SW_WO_OFF;
  const float* boutp = (const float*)(sw + SW_TOTAL);
  const f32x4 z4 = {0.f, 0.f, 0.f, 0.f};

  const int mq = wave >> 1;   // m-quarter (4 m-tiles) for G1/G2
  const int nh = wave & 1;    // batch-half (4 batch-tiles) for G1/G2

  for (int it = 0; it <= IT; ++it){
    const int row0W = (blockIdx.x * IT + it) * ROWS;
    const int row0E = (blockIdx.x * IT + it - 1) * ROWS;
    const bool doW = isW && (it < IT);
    const bool doE = (!isW) && (it > 0);

    // ---- epilogue state (E waves), per iteration
    bf16x8 ev0[2], ev1[2], ev2[2];
    f32x2 xyk_s[2], whk_s[2];
    float zk_s[2], zk1_s[2], xv_s[2];
    bool  msk_s[2];
    f32x4 acc2[4][4];                  // G2 accumulator, spans S1..S3 (W)

    // ================= interval pre-S1 =================
    if (doW){
      // GEMM1 (transposed): h1[b][m] = relu(W0'^T x2 + b0)
      bf16x8 bfr[4];
      #pragma unroll
      for (int nt = 0; nt < 4; nt++){
        bf16x8 b = {};                   // k=quad*8+j; only quad 0 (k<8) real
        if (quad == 0){
          const float* xp = x + (long)(row0W + (nh*4 + nt)*16 + l16)*16 + 8;
          float4 u = *(const float4*)xp;
          float4 v = *(const float4*)(xp + 4);
          f32x8 xf; xf[0]=u.x; xf[1]=u.y; xf[2]=u.z; xf[3]=u.w;
                    xf[4]=v.x; xf[5]=v.y; xf[6]=v.z; xf[7]=v.w;
          b = __builtin_convertvector(xf, bf16x8);
        }
        bfr[nt] = b;
      }
      #pragma unroll
      for (int mi = 0; mi < 4; mi++){
        int mt = mq*4 + mi;
        bf16x8 a = *(const bf16x8*)(sw + (mt*64 + lane)*8);
        float4 bb = *(const float4*)(b0v + mt*16 + quad*4);
        #pragma unroll
        for (int nt = 0; nt < 4; nt++){
          f32x4 acc = MFMA16(a, bfr[nt], z4);
          *(bf16x4v*)(hbuf + ((nh*4+nt)*16 + l16)*HSTRIDE + mt*16 + quad*4) = relu_cvt4(acc, bb);
        }
      }
    } else if (doE){
      // x2 passthrough for the previous tile (R8 store pattern, proven 35 MB)
      if (tid2 < 2*ROWS){
        int r = tid2 >> 1, hf = tid2 & 1;
        long g = (long)row0E + r;
        *(float4*)(out + g*16 + 8 + hf*4) = *(const float4*)(x + g*16 + 8 + hf*4);
      }
      // hoist raw -> registers (frees rawb for this iter's G3 store)
      #pragma unroll
      for (int pp = 0; pp < 2; pp++){
        int p   = tid2 + pp*512;
        int row = p >> 3;
        int t   = p & 7;
        const __bf16* rr = rawb + row*HSTRIDE + t*24;
        ev0[pp] = *(const bf16x8*)(rr);
        ev1[pp] = *(const bf16x8*)(rr + 8);
        ev2[pp] = *(const bf16x8*)(rr + 16);
        xv_s[pp] = x[((long)row0E + row)*16 + t];
      }
    }
    __syncthreads();   // S1: h1 complete / rawb free

    // ================= interval S1-S2 =================
    if (doW){
      // GEMM2 k-loop: acc2 = W1'^T h1
      #pragma unroll
      for (int mi=0;mi<4;mi++)
        #pragma unroll
        for (int bt=0;bt<4;bt++) acc2[mi][bt] = z4;
      #pragma unroll
      for (int kb=0;kb<8;kb++){
        bf16x8 hf[4];
        #pragma unroll
        for (int bt=0;bt<4;bt++)
          hf[bt] = *(const bf16x8*)(hbuf + ((nh*4+bt)*16 + l16)*HSTRIDE + kb*32 + quad*8);
        #pragma unroll
        for (int mi=0;mi<4;mi++){
          bf16x8 a = *(const bf16x8*)(swW1 + ((kb*16 + mq*4 + mi)*64 + lane)*8);
          #pragma unroll
          for (int bt=0;bt<4;bt++)
            acc2[mi][bt] = MFMA16(a, hf[bt], acc2[mi][bt]);
        }
      }
    } else if (doE){
      // epilogue chunk A: exp2 + packed scan (heavy; overlaps G2 MFMAs)
      #pragma unroll
      for (int pp = 0; pp < 2; pp++){
        f32x2 ewh[8];
        f32x2 sum = {0.f, 0.f};
        #pragma unroll
        for (int i=0;i<8;i++){
          f32x2 e;
          e[0] = __builtin_amdgcn_exp2f((float)ev0[pp][i]);
          e[1] = __builtin_amdgcn_exp2f((float)ev1[pp][i]);
          ewh[i] = e; sum += e;
        }
        f32x2 scale;
        scale[0] = 1.9984f * __builtin_amdgcn_rcpf(sum[0]);
        scale[1] = 1.9984f * __builtin_amdgcn_rcpf(sum[1]);
        const f32x2 off2 = {2e-4f, 2e-4f};

        float xv = xv_s[pp];
        bool msk = (xv <= -0.999f) || (xv >= 0.999f);
        float xin = msk ? 0.f : xv;

        f32x2 whi = ewh[0]*scale + off2;
        f32x2 ec; ec[0] = -1.f + whi[0]; ec[1] = -1.f + whi[1];
        f32x2 xyk = {-1.f, -1.f};
        f32x2 whk = whi;
        float zk = ZSENT, zk1 = (float)ev2[pp][0];
        #pragma unroll
        for (int i=1;i<8;i++){
          whi = ewh[i]*scale + off2;
          bool le = (ec[0] <= xin);
          xyk = le ? ec : xyk;
          whk = le ? whi : whk;
          zk  = le ? (float)ev2[pp][i-1] : zk;
          zk1 = le ? ((i==7) ? ZSENT : (float)ev2[pp][i]) : zk1;
          ec += whi;
        }
        xyk_s[pp] = xyk; whk_s[pp] = whk;
        zk_s[pp] = zk; zk1_s[pp] = zk1; msk_s[pp] = msk;
      }
    }
    __syncthreads();   // S2: h1 reads complete, hbuf free for h2

    // ================= interval S2-S3 =================
    if (doW){
      // GEMM2 stores: h2 = relu(acc2 + b1)
      #pragma unroll
      for (int mi=0;mi<4;mi++){
        int mt = mq*4 + mi;
        float4 bb = *(const float4*)(b1v + mt*16 + quad*4);
        #pragma unroll
        for (int bt=0;bt<4;bt++)
          *(bf16x4v*)(hbuf + ((nh*4+bt)*16 + l16)*HSTRIDE + mt*16 + quad*4) =
              relu_cvt4(acc2[mi][bt], bb);
      }
    }
    __syncthreads();   // S3: h2 complete

    // ================= interval S3-S5 =================
    if (doW){
      // GEMM3 (192 padded cols): raw(t) = Wout'^T h2 + bout' -> rawb
      const int nc = wave & 3;
      const int mh = wave >> 2;
      f32x4 acc[4][3];                     // [bt][mi]
      #pragma unroll
      for (int bt=0;bt<4;bt++)
        #pragma unroll
        for (int mi=0;mi<3;mi++) acc[bt][mi] = z4;
      #pragma unroll
      for (int kb=0;kb<8;kb++){
        bf16x8 hf[4];
        #pragma unroll
        for (int bt=0;bt<4;bt++)
          hf[bt] = *(const bf16x8*)(hbuf + ((mh*4+bt)*16 + l16)*HSTRIDE + kb*32 + quad*8);
        #pragma unroll
        for (int mi=0;mi<3;mi++){
          bf16x8 a = *(const bf16x8*)(swWo + ((kb*12 + nc*3 + mi)*64 + lane)*8);
          #pragma unroll
          for (int bt=0;bt<4;bt++)
            acc[bt][mi] = MFMA16(a, hf[bt], acc[bt][mi]);
        }
      }
      // store to separate rawb: no barrier needed (different buffer)
      #pragma unroll
      for (int mi=0;mi<3;mi++){
        int mt = nc*3 + mi;
        float4 bb = *(const float4*)(boutp + mt*16 + quad*4);
        #pragma unroll
        for (int bt=0;bt<4;bt++){
          int row = (mh*4+bt)*16 + l16;
          *(bf16x4v*)(rawb + row*HSTRIDE + mt*16 + quad*4) = add_cvt4(acc[bt][mi], bb);
        }
      }
    } else if (doE){
      // epilogue chunk B: softplus + spline + stores (overlaps G3 MFMAs)
      float ldv[2];
      #pragma unroll
      for (int pp = 0; pp < 2; pp++){
        int p   = tid2 + pp*512;
        int row = p >> 3;
        int t   = p & 7;
        long gr = row0E + row;
        float xv = xv_s[pp];
        bool msk = msk_s[pp];
        float xin = msk ? 0.f : xv;
        f32x2 xyk = xyk_s[pp], whk = whk_s[pp];

        float za = zk_s[pp] + SPCONST, zb = zk1_s[pp] + SPCONST;
        float dk  = (fmaxf(za,0.f) + __builtin_amdgcn_logf(1.f + __builtin_amdgcn_exp2f(-fabsf(za))))*LN2 + 1e-4f;
        float dk1 = (fmaxf(zb,0.f) + __builtin_amdgcn_logf(1.f + __builtin_amdgcn_exp2f(-fabsf(zb))))*LN2 + 1e-4f;

        float rwk = __builtin_amdgcn_rcpf(whk[0]);
        float sk  = whk[1] * rwk;
        float eps = (xin - xyk[0]) * rwk;
        float om  = 1.f - eps;
        float et  = eps * om;
        float e2  = eps * eps;
        float beta  = sk + (dk1 + dk - 2.f*sk) * et;
        float rb    = __builtin_amdgcn_rcpf(beta);
        float alpha = whk[1] * (sk*e2 + dk*et);
        float yv  = msk ? xv : (xyk[1] + alpha * rb);
        float num = dk1*e2 + 2.f*sk*et + dk*om*om;
        float ld  = msk ? 0.f : __builtin_amdgcn_logf(sk*sk*num*rb*rb) * LN2;

        out[gr*16 + t] = yv;
        ldv[pp] = ld;
      }
      // per-row logdet: 8 t-lanes adjacent -> 3-step shfl_xor reduction
      float s0 = ldv[0], s1 = ldv[1];
      #pragma unroll
      for (int m = 1; m < 8; m <<= 1){
        s0 += __shfl_xor(s0, m);
        s1 += __shfl_xor(s1, m);
      }
      if ((lane & 7) == 0){
        int r = tid2 >> 3;               // 0..63
        out[(long)nrows*16 + row0E + r]      = s0;
        out[(long)nrows*16 + row0E + r + 64] = s1;
      }
    }
    __syncthreads();   // S5: raw(t) complete; consumed by E next iteration
  }
}

extern "C" void kernel_launch(void* const* d_in, const int* in_sizes, int n_in,
                              void* d_out, int out_size, void* d_ws, size_t ws_size,
                              hipStream_t stream)
{
  const float* x    = (const float*)d_in[0];
  const float* W0   = (const float*)d_in[1];
  const float* b0   = (const float*)d_in[2];
  const float* W1   = (const float*)d_in[3];
  const float* b1   = (const float*)d_in[4];
  const float* Wout = (const float*)d_in[5];
  const float* bout = (const float*)d_in[6];
  float* out = (float*)d_out;
  __bf16* sw = (__bf16*)d_ws;

  int nrows  = in_sizes[0] / 16;         // 524288
  int ntiles = nrows / ROWS;             // 4096
  int nblk   = ntiles / IT;              // 512

  prep_kernel<<<(SW_TOTAL + 192 + 255)/256, 256, 0, stream>>>(W0, W1, Wout, bout, sw);
  fused_kernel<<<nblk, 1024, 0, stream>>>(x, b0, b1, sw, out, nrows);
}

// Round 6
// 723.719 us; speedup vs baseline: 1.0829x; 1.0829x over previous
//
#include <hip/hip_runtime.h>
#include <hip/hip_bf16.h>

// CouplingSplineLayer fused kernel for MI355X (gfx950), round 14.
// R14 = R13's wave-specialized pipeline with the scratch-spill designed out:
//  * LDS ping-pong (H/R swap per iter) replaces in-place h1->h2, so GEMM2's
//    k-loop and its h2 store live in ONE barrier interval -- no f32x4
//    accumulator crosses a barrier anywhere (R13's acc2 spanned two).
//  * Waves 0-7 = GEMM (R8 mappings verbatim), waves 8-15 = epilogue of the
//    previous tile (R8 arithmetic verbatim). 3 barriers/iter.
//  * E-wave cross-barrier state: ev* (24 VGPR) across S1, 16-reg scan state
//    across S2. Peak pressure ~116 < 128 cap at launch_bounds(1024,4).
//  * Per-row traffic identical to R8 on every path (weights, LDS, HBM).

typedef __bf16 bf16x8 __attribute__((ext_vector_type(8)));
typedef __bf16 bf16x4v __attribute__((ext_vector_type(4)));
typedef float  f32x8 __attribute__((ext_vector_type(8)));
typedef float  f32x4 __attribute__((ext_vector_type(4)));
typedef float  f32x2 __attribute__((ext_vector_type(2)));

#define MFMA16(a,b,c) __builtin_amdgcn_mfma_f32_16x16x32_bf16((a),(b),(c),0,0,0)

#define SW_W1_OFF 8192      // W0: 1 kb * 16 tiles * 512
#define SW_WO_OFF 73728     // W1: 8 kb * 16 tiles * 512
#define SW_TOTAL  122880    // Wout': 8 kb * 12 tiles * 512 (192 padded cols)
// float bout'[192] lives at d_ws + SW_TOTAL*2 bytes

#define ROWS    128
#define IT      8           // row-tiles per block
#define HSTRIDE 264         // h row stride in bf16 (528 B: 16B-aligned)
#define LOG2E   1.44269504f
#define LN2     0.69314718f
#define SPCONST 0.7806568f      // log(exp(1-1e-4)-1) * log2e
#define ZSENT  (-0.00015680f)   // raw-z sentinel whose softplus-chain -> d = 1

__global__ void prep_kernel(const float* __restrict__ W0,
                            const float* __restrict__ W1,
                            const float* __restrict__ Wout,
                            const float* __restrict__ bout,
                            __bf16* __restrict__ sw)
{
  int i = blockIdx.x * 256 + threadIdx.x;
  if (i >= SW_TOTAL + 192) return;
  if (i >= SW_TOTAL){                      // bout'[192] remap (float, *log2e)
    int np = i - SW_TOTAL;
    int t = np / 24, p = np % 24;
    float* boutp = (float*)(sw + SW_TOTAL);
    boutp[np] = (p < 23) ? bout[t*23 + p] * LOG2E : 0.f;
    return;
  }
  const float* src; int K, N, NT, li;
  bool wo = false;
  if (i < SW_W1_OFF)      { src = W0;   K = 8;   N = 256; NT = 16; li = i; }
  else if (i < SW_WO_OFF) { src = W1;   K = 256; N = 256; NT = 16; li = i - SW_W1_OFF; }
  else { src = Wout; K = 256; N = 184; NT = 12; li = i - SW_WO_OFF; wo = true; }
  int j    = li & 7;
  int l    = (li >> 3) & 63;
  int rest = li >> 9;
  int nt   = rest % NT;
  int kb   = rest / NT;
  int k = kb * 32 + ((l >> 4) << 3) + j;
  int n = nt * 16 + (l & 15);
  float v;
  if (wo){
    int t = n / 24, p = n % 24;            // n is padded col n' in 0..191
    v = (p < 23 && k < K) ? Wout[k*184 + t*23 + p] * LOG2E : 0.f;
  } else {
    v = (k < K && n < N) ? src[k * N + n] : 0.f;
  }
  sw[i] = (__bf16)v;
}

__device__ __forceinline__ bf16x4v relu_cvt4(f32x4 acc, float4 bb){
  f32x4 s;
  s[0] = acc[0] + bb.x; s[1] = acc[1] + bb.y;
  s[2] = acc[2] + bb.z; s[3] = acc[3] + bb.w;
  f32x4 z = {0.f, 0.f, 0.f, 0.f};
  s = __builtin_elementwise_max(s, z);
  return __builtin_convertvector(s, bf16x4v);   // v_cvt_pk_bf16_f32 x2
}

__device__ __forceinline__ bf16x4v add_cvt4(f32x4 acc, float4 bb){
  f32x4 s;
  s[0] = acc[0] + bb.x; s[1] = acc[1] + bb.y;
  s[2] = acc[2] + bb.z; s[3] = acc[3] + bb.w;
  return __builtin_convertvector(s, bf16x4v);
}

__global__ __launch_bounds__(1024, 4)
void fused_kernel(const float* __restrict__ x,
                  const float* __restrict__ b0v,
                  const float* __restrict__ b1v,
                  const __bf16* __restrict__ sw,
                  float* __restrict__ out,
                  int nrows)
{
  __shared__ __align__(16) unsigned char smemA[ROWS * HSTRIDE * 2];
  __shared__ __align__(16) unsigned char smemB[ROWS * HSTRIDE * 2];
  __bf16* H = (__bf16*)smemA;   // h1 target; G3 writes raw(t) here
  __bf16* R = (__bf16*)smemB;   // holds raw(t-1) at iter start; h2 target

  const int tid  = threadIdx.x;
  const int wave = tid >> 6;          // 0..15
  const bool isW = wave < 8;          // GEMM waves
  const int lane = tid & 63;
  const int quad = lane >> 4;
  const int l16  = lane & 15;
  const int tid2 = tid - 512;         // epilogue-thread index [0,512)

  const __bf16* swW1 = sw + SW_W1_OFF;
  const __bf16* swWo = sw + SW_WO_OFF;
  const float* boutp = (const float*)(sw + SW_TOTAL);
  const f32x4 z4 = {0.f, 0.f, 0.f, 0.f};

  const int mq = wave >> 1;   // m-quarter (4 m-tiles) for G1/G2
  const int nh = wave & 1;    // batch-half (4 batch-tiles) for G1/G2
  const int nc = wave & 3;    // G3 n'-group
  const int mh = wave >> 2;   // G3 batch-half (0..1 over waves 0..7)

  for (int it = 0; it <= IT; ++it){
    const long row0W = (long)(blockIdx.x * IT + it) * ROWS;
    const long row0E = (long)(blockIdx.x * IT + it - 1) * ROWS;
    const bool doW = isW && (it < IT);
    const bool doE = (!isW) && (it > 0);

    // E-wave pipeline registers
    bf16x8 ev0[2], ev1[2], ev2[2];
    float  xv_s[2];
    f32x2  xyk_s[2], whk_s[2];
    float  zk_s[2], zk1_s[2];
    bool   msk_s[2];

    // ================= pre-S1: G1 -> H  ||  E: passthrough + hoist from R
    if (doW){
      bf16x8 bfr[4];
      #pragma unroll
      for (int nt = 0; nt < 4; nt++){
        bf16x8 b = {};                   // k=quad*8+j; only quad 0 (k<8) real
        if (quad == 0){
          const float* xp = x + (row0W + (nh*4 + nt)*16 + l16)*16 + 8;
          float4 u = *(const float4*)xp;
          float4 v = *(const float4*)(xp + 4);
          f32x8 xf; xf[0]=u.x; xf[1]=u.y; xf[2]=u.z; xf[3]=u.w;
                    xf[4]=v.x; xf[5]=v.y; xf[6]=v.z; xf[7]=v.w;
          b = __builtin_convertvector(xf, bf16x8);
        }
        bfr[nt] = b;
      }
      #pragma unroll
      for (int mi = 0; mi < 4; mi++){
        int mt = mq*4 + mi;
        bf16x8 a = *(const bf16x8*)(sw + (mt*64 + lane)*8);
        float4 bb = *(const float4*)(b0v + mt*16 + quad*4);
        #pragma unroll
        for (int nt = 0; nt < 4; nt++){
          f32x4 acc = MFMA16(a, bfr[nt], z4);
          *(bf16x4v*)(H + ((nh*4+nt)*16 + l16)*HSTRIDE + mt*16 + quad*4) = relu_cvt4(acc, bb);
        }
      }
    } else if (doE){
      if (tid2 < 2*ROWS){
        int r = tid2 >> 1, hf = tid2 & 1;
        long g = row0E + r;
        *(float4*)(out + g*16 + 8 + hf*4) = *(const float4*)(x + g*16 + 8 + hf*4);
      }
      #pragma unroll
      for (int pp = 0; pp < 2; pp++){
        int p   = tid2 + pp*512;
        int row = p >> 3;
        int t   = p & 7;
        const __bf16* rr = R + row*HSTRIDE + t*24;
        ev0[pp] = *(const bf16x8*)(rr);
        ev1[pp] = *(const bf16x8*)(rr + 8);
        ev2[pp] = *(const bf16x8*)(rr + 16);
        xv_s[pp] = x[(row0E + row)*16 + t];
      }
    }
    __syncthreads();   // S1: h1 in H complete; R hoisted (free)

    // ================= S1-S2: G2 reads H, writes h2 -> R  ||  E: exp2+scan
    if (doW){
      f32x4 acc2[4][4];                  // interval-local: NO barrier crossing
      #pragma unroll
      for (int mi=0;mi<4;mi++)
        #pragma unroll
        for (int bt=0;bt<4;bt++) acc2[mi][bt] = z4;
      #pragma unroll
      for (int kb=0;kb<8;kb++){
        bf16x8 hf[4];
        #pragma unroll
        for (int bt=0;bt<4;bt++)
          hf[bt] = *(const bf16x8*)(H + ((nh*4+bt)*16 + l16)*HSTRIDE + kb*32 + quad*8);
        #pragma unroll
        for (int mi=0;mi<4;mi++){
          bf16x8 a = *(const bf16x8*)(swW1 + ((kb*16 + mq*4 + mi)*64 + lane)*8);
          #pragma unroll
          for (int bt=0;bt<4;bt++)
            acc2[mi][bt] = MFMA16(a, hf[bt], acc2[mi][bt]);
        }
      }
      #pragma unroll
      for (int mi=0;mi<4;mi++){
        int mt = mq*4 + mi;
        float4 bb = *(const float4*)(b1v + mt*16 + quad*4);
        #pragma unroll
        for (int bt=0;bt<4;bt++)
          *(bf16x4v*)(R + ((nh*4+bt)*16 + l16)*HSTRIDE + mt*16 + quad*4) =
              relu_cvt4(acc2[mi][bt], bb);
      }
    } else if (doE){
      #pragma unroll
      for (int pp = 0; pp < 2; pp++){
        f32x2 ewh[8];
        f32x2 sum = {0.f, 0.f};
        #pragma unroll
        for (int i=0;i<8;i++){
          f32x2 e;
          e[0] = __builtin_amdgcn_exp2f((float)ev0[pp][i]);
          e[1] = __builtin_amdgcn_exp2f((float)ev1[pp][i]);
          ewh[i] = e; sum += e;
        }
        f32x2 scale;
        scale[0] = 1.9984f * __builtin_amdgcn_rcpf(sum[0]);
        scale[1] = 1.9984f * __builtin_amdgcn_rcpf(sum[1]);
        const f32x2 off2 = {2e-4f, 2e-4f};

        float xv = xv_s[pp];
        bool msk = (xv <= -0.999f) || (xv >= 0.999f);
        float xin = msk ? 0.f : xv;

        f32x2 whi = ewh[0]*scale + off2;
        f32x2 ec; ec[0] = -1.f + whi[0]; ec[1] = -1.f + whi[1];
        f32x2 xyk = {-1.f, -1.f};
        f32x2 whk = whi;
        float zk = ZSENT, zk1 = (float)ev2[pp][0];
        #pragma unroll
        for (int i=1;i<8;i++){
          whi = ewh[i]*scale + off2;
          bool le = (ec[0] <= xin);
          xyk = le ? ec : xyk;
          whk = le ? whi : whk;
          zk  = le ? (float)ev2[pp][i-1] : zk;
          zk1 = le ? ((i==7) ? ZSENT : (float)ev2[pp][i]) : zk1;
          ec += whi;
        }
        xyk_s[pp] = xyk; whk_s[pp] = whk;
        zk_s[pp] = zk; zk1_s[pp] = zk1; msk_s[pp] = msk;
      }
    }
    __syncthreads();   // S2: h2 in R complete

    // ================= S2-S3: G3 reads R, writes raw -> H  ||  E: spline
    if (doW){
      f32x4 acc[4][3];                   // interval-local
      #pragma unroll
      for (int bt=0;bt<4;bt++)
        #pragma unroll
        for (int mi=0;mi<3;mi++) acc[bt][mi] = z4;
      #pragma unroll
      for (int kb=0;kb<8;kb++){
        bf16x8 hf[4];
        #pragma unroll
        for (int bt=0;bt<4;bt++)
          hf[bt] = *(const bf16x8*)(R + ((mh*4+bt)*16 + l16)*HSTRIDE + kb*32 + quad*8);
        #pragma unroll
        for (int mi=0;mi<3;mi++){
          bf16x8 a = *(const bf16x8*)(swWo + ((kb*12 + nc*3 + mi)*64 + lane)*8);
          #pragma unroll
          for (int bt=0;bt<4;bt++)
            acc[bt][mi] = MFMA16(a, hf[bt], acc[bt][mi]);
        }
      }
      #pragma unroll
      for (int mi=0;mi<3;mi++){
        int mt = nc*3 + mi;
        float4 bb = *(const float4*)(boutp + mt*16 + quad*4);
        #pragma unroll
        for (int bt=0;bt<4;bt++){
          int row = (mh*4+bt)*16 + l16;
          *(bf16x4v*)(H + row*HSTRIDE + mt*16 + quad*4) = add_cvt4(acc[bt][mi], bb);
        }
      }
    } else if (doE){
      float ldv[2];
      #pragma unroll
      for (int pp = 0; pp < 2; pp++){
        int p   = tid2 + pp*512;
        int row = p >> 3;
        int t   = p & 7;
        long gr = row0E + row;
        float xv = xv_s[pp];
        bool msk = msk_s[pp];
        float xin = msk ? 0.f : xv;
        f32x2 xyk = xyk_s[pp], whk = whk_s[pp];

        float za = zk_s[pp] + SPCONST, zb = zk1_s[pp] + SPCONST;
        float dk  = (fmaxf(za,0.f) + __builtin_amdgcn_logf(1.f + __builtin_amdgcn_exp2f(-fabsf(za))))*LN2 + 1e-4f;
        float dk1 = (fmaxf(zb,0.f) + __builtin_amdgcn_logf(1.f + __builtin_amdgcn_exp2f(-fabsf(zb))))*LN2 + 1e-4f;

        float rwk = __builtin_amdgcn_rcpf(whk[0]);
        float sk  = whk[1] * rwk;
        float eps = (xin - xyk[0]) * rwk;
        float om  = 1.f - eps;
        float et  = eps * om;
        float e2  = eps * eps;
        float beta  = sk + (dk1 + dk - 2.f*sk) * et;
        float rb    = __builtin_amdgcn_rcpf(beta);
        float alpha = whk[1] * (sk*e2 + dk*et);
        float yv  = msk ? xv : (xyk[1] + alpha * rb);
        float num = dk1*e2 + 2.f*sk*et + dk*om*om;
        float ld  = msk ? 0.f : __builtin_amdgcn_logf(sk*sk*num*rb*rb) * LN2;

        out[gr*16 + t] = yv;
        ldv[pp] = ld;
      }
      float s0 = ldv[0], s1 = ldv[1];
      #pragma unroll
      for (int m = 1; m < 8; m <<= 1){
        s0 += __shfl_xor(s0, m);
        s1 += __shfl_xor(s1, m);
      }
      if ((lane & 7) == 0){
        int r = tid2 >> 3;               // 0..63
        out[(long)nrows*16 + row0E + r]      = s0;
        out[(long)nrows*16 + row0E + r + 64] = s1;
      }
    }
    __syncthreads();   // S3: raw(t) in H complete

    __bf16* tmp = H; H = R; R = tmp;     // raw(t) becomes next iter's R
  }
}

extern "C" void kernel_launch(void* const* d_in, const int* in_sizes, int n_in,
                              void* d_out, int out_size, void* d_ws, size_t ws_size,
                              hipStream_t stream)
{
  const float* x    = (const float*)d_in[0];
  const float* W0   = (const float*)d_in[1];
  const float* b0   = (const float*)d_in[2];
  const float* W1   = (const float*)d_in[3];
  const float* b1   = (const float*)d_in[4];
  const float* Wout = (const float*)d_in[5];
  const float* bout = (const float*)d_in[6];
  float* out = (float*)d_out;
  __bf16* sw = (__bf16*)d_ws;

  int nrows  = in_sizes[0] / 16;         // 524288
  int ntiles = nrows / ROWS;             // 4096
  int nblk   = ntiles / IT;              // 512

  prep_kernel<<<(SW_TOTAL + 192 + 255)/256, 256, 0, stream>>>(W0, W1, Wout, bout, sw);
  fused_kernel<<<nblk, 1024, 0, stream>>>(x, b0, b1, sw, out, nrows);
}

// Round 7
// 711.835 us; speedup vs baseline: 1.1010x; 1.0167x over previous
//
#include <hip/hip_runtime.h>
#include <hip/hip_bf16.h>

// CouplingSplineLayer fused kernel for MI355X (gfx950), round 15.
// R15 = R14 (wave-specialized pipeline, arithmetic verbatim) with the
// register-allocator cap removed:
//  * __launch_bounds__(1024) with NO min-occupancy arg. R13/R14 compiled at
//    exactly the 64-VGPR cap implied by the ",4" argument and spilled the
//    E-wave cross-barrier state (~1.4 GB scratch traffic, FETCH 0.8-1 GB).
//    LDS (132 KB) already limits residency to 1 block/CU, so the cap bought
//    nothing. Natural usage ~110 VGPR < 256: no spill expected.
//  * Parity-indexed LDS buffer offsets (no pointer swap across iterations).
//  * IT=16 -> 256 blocks = exactly 1 per CU (fill/drain 5.9% vs 12.5%).
// Structure: waves 0-7 = GEMM (R8 mappings), waves 8-15 = epilogue of the
// previous tile, LDS ping-pong H/R, 3 barriers/iter. All per-row traffic
// identical to R8.

typedef __bf16 bf16x8 __attribute__((ext_vector_type(8)));
typedef __bf16 bf16x4v __attribute__((ext_vector_type(4)));
typedef float  f32x8 __attribute__((ext_vector_type(8)));
typedef float  f32x4 __attribute__((ext_vector_type(4)));
typedef float  f32x2 __attribute__((ext_vector_type(2)));

#define MFMA16(a,b,c) __builtin_amdgcn_mfma_f32_16x16x32_bf16((a),(b),(c),0,0,0)

#define SW_W1_OFF 8192      // W0: 1 kb * 16 tiles * 512
#define SW_WO_OFF 73728     // W1: 8 kb * 16 tiles * 512
#define SW_TOTAL  122880    // Wout': 8 kb * 12 tiles * 512 (192 padded cols)
// float bout'[192] lives at d_ws + SW_TOTAL*2 bytes

#define ROWS    128
#define IT      16          // row-tiles per block -> 256 blocks = 1/CU
#define HSTRIDE 264         // h row stride in bf16 (528 B: 16B-aligned)
#define HELEMS  (ROWS*HSTRIDE)
#define LOG2E   1.44269504f
#define LN2     0.69314718f
#define SPCONST 0.7806568f      // log(exp(1-1e-4)-1) * log2e
#define ZSENT  (-0.00015680f)   // raw-z sentinel whose softplus-chain -> d = 1

__global__ void prep_kernel(const float* __restrict__ W0,
                            const float* __restrict__ W1,
                            const float* __restrict__ Wout,
                            const float* __restrict__ bout,
                            __bf16* __restrict__ sw)
{
  int i = blockIdx.x * 256 + threadIdx.x;
  if (i >= SW_TOTAL + 192) return;
  if (i >= SW_TOTAL){                      // bout'[192] remap (float, *log2e)
    int np = i - SW_TOTAL;
    int t = np / 24, p = np % 24;
    float* boutp = (float*)(sw + SW_TOTAL);
    boutp[np] = (p < 23) ? bout[t*23 + p] * LOG2E : 0.f;
    return;
  }
  const float* src; int K, N, NT, li;
  bool wo = false;
  if (i < SW_W1_OFF)      { src = W0;   K = 8;   N = 256; NT = 16; li = i; }
  else if (i < SW_WO_OFF) { src = W1;   K = 256; N = 256; NT = 16; li = i - SW_W1_OFF; }
  else { src = Wout; K = 256; N = 184; NT = 12; li = i - SW_WO_OFF; wo = true; }
  int j    = li & 7;
  int l    = (li >> 3) & 63;
  int rest = li >> 9;
  int nt   = rest % NT;
  int kb   = rest / NT;
  int k = kb * 32 + ((l >> 4) << 3) + j;
  int n = nt * 16 + (l & 15);
  float v;
  if (wo){
    int t = n / 24, p = n % 24;            // n is padded col n' in 0..191
    v = (p < 23 && k < K) ? Wout[k*184 + t*23 + p] * LOG2E : 0.f;
  } else {
    v = (k < K && n < N) ? src[k * N + n] : 0.f;
  }
  sw[i] = (__bf16)v;
}

__device__ __forceinline__ bf16x4v relu_cvt4(f32x4 acc, float4 bb){
  f32x4 s;
  s[0] = acc[0] + bb.x; s[1] = acc[1] + bb.y;
  s[2] = acc[2] + bb.z; s[3] = acc[3] + bb.w;
  f32x4 z = {0.f, 0.f, 0.f, 0.f};
  s = __builtin_elementwise_max(s, z);
  return __builtin_convertvector(s, bf16x4v);   // v_cvt_pk_bf16_f32 x2
}

__device__ __forceinline__ bf16x4v add_cvt4(f32x4 acc, float4 bb){
  f32x4 s;
  s[0] = acc[0] + bb.x; s[1] = acc[1] + bb.y;
  s[2] = acc[2] + bb.z; s[3] = acc[3] + bb.w;
  return __builtin_convertvector(s, bf16x4v);
}

__global__ __launch_bounds__(1024)
void fused_kernel(const float* __restrict__ x,
                  const float* __restrict__ b0v,
                  const float* __restrict__ b1v,
                  const __bf16* __restrict__ sw,
                  float* __restrict__ out,
                  int nrows)
{
  __shared__ __align__(16) __bf16 smem[2*HELEMS];   // 135168 B -> 1 block/CU

  const int tid  = threadIdx.x;
  const int wave = tid >> 6;          // 0..15
  const bool isW = wave < 8;          // GEMM waves
  const int lane = tid & 63;
  const int quad = lane >> 4;
  const int l16  = lane & 15;
  const int tid2 = tid - 512;         // epilogue-thread index [0,512)

  const __bf16* swW1 = sw + SW_W1_OFF;
  const __bf16* swWo = sw + SW_WO_OFF;
  const float* boutp = (const float*)(sw + SW_TOTAL);
  const f32x4 z4 = {0.f, 0.f, 0.f, 0.f};

  const int mq = wave >> 1;   // m-quarter (4 m-tiles) for G1/G2
  const int nh = wave & 1;    // batch-half (4 batch-tiles) for G1/G2
  const int nc = wave & 3;    // G3 n'-group
  const int mh = wave >> 2;   // G3 batch-half (0..1 over waves 0..7)

  for (int it = 0; it <= IT; ++it){
    const long row0W = (long)(blockIdx.x * IT + it) * ROWS;
    const long row0E = row0W - ROWS;
    const bool doW = isW && (it < IT);
    const bool doE = (!isW) && (it > 0);
    const int par = it & 1;
    __bf16* H = smem + par*HELEMS;        // G1 h1 target; G3 raw(t) target
    __bf16* R = smem + (par^1)*HELEMS;    // raw(t-1) at iter start; h2 target

    // E-wave pipeline registers (interval-local except across S1/S2)
    bf16x8 ev0[2], ev1[2], ev2[2];
    float  xv_s[2];
    f32x2  xyk_s[2], whk_s[2];
    float  zk_s[2], zk1_s[2];
    bool   msk_s[2];

    // ================= pre-S1: G1 -> H  ||  E: passthrough + hoist from R
    if (doW){
      bf16x8 bfr[4];
      #pragma unroll
      for (int nt = 0; nt < 4; nt++){
        bf16x8 b = {};                   // k=quad*8+j; only quad 0 (k<8) real
        if (quad == 0){
          const float* xp = x + (row0W + (nh*4 + nt)*16 + l16)*16 + 8;
          float4 u = *(const float4*)xp;
          float4 v = *(const float4*)(xp + 4);
          f32x8 xf; xf[0]=u.x; xf[1]=u.y; xf[2]=u.z; xf[3]=u.w;
                    xf[4]=v.x; xf[5]=v.y; xf[6]=v.z; xf[7]=v.w;
          b = __builtin_convertvector(xf, bf16x8);
        }
        bfr[nt] = b;
      }
      #pragma unroll
      for (int mi = 0; mi < 4; mi++){
        int mt = mq*4 + mi;
        bf16x8 a = *(const bf16x8*)(sw + (mt*64 + lane)*8);
        float4 bb = *(const float4*)(b0v + mt*16 + quad*4);
        #pragma unroll
        for (int nt = 0; nt < 4; nt++){
          f32x4 acc = MFMA16(a, bfr[nt], z4);
          *(bf16x4v*)(H + ((nh*4+nt)*16 + l16)*HSTRIDE + mt*16 + quad*4) = relu_cvt4(acc, bb);
        }
      }
    } else if (doE){
      if (tid2 < 2*ROWS){
        int r = tid2 >> 1, hf = tid2 & 1;
        long g = row0E + r;
        *(float4*)(out + g*16 + 8 + hf*4) = *(const float4*)(x + g*16 + 8 + hf*4);
      }
      #pragma unroll
      for (int pp = 0; pp < 2; pp++){
        int p   = tid2 + pp*512;
        int row = p >> 3;
        int t   = p & 7;
        const __bf16* rr = R + row*HSTRIDE + t*24;
        ev0[pp] = *(const bf16x8*)(rr);
        ev1[pp] = *(const bf16x8*)(rr + 8);
        ev2[pp] = *(const bf16x8*)(rr + 16);
        xv_s[pp] = x[(row0E + row)*16 + t];
      }
    }
    __syncthreads();   // S1: h1 in H complete; R hoisted (free)

    // ================= S1-S2: G2 reads H, writes h2 -> R  ||  E: exp2+scan
    if (doW){
      f32x4 acc2[4][4];                  // interval-local
      #pragma unroll
      for (int mi=0;mi<4;mi++)
        #pragma unroll
        for (int bt=0;bt<4;bt++) acc2[mi][bt] = z4;
      #pragma unroll
      for (int kb=0;kb<8;kb++){
        bf16x8 hf[4];
        #pragma unroll
        for (int bt=0;bt<4;bt++)
          hf[bt] = *(const bf16x8*)(H + ((nh*4+bt)*16 + l16)*HSTRIDE + kb*32 + quad*8);
        #pragma unroll
        for (int mi=0;mi<4;mi++){
          bf16x8 a = *(const bf16x8*)(swW1 + ((kb*16 + mq*4 + mi)*64 + lane)*8);
          #pragma unroll
          for (int bt=0;bt<4;bt++)
            acc2[mi][bt] = MFMA16(a, hf[bt], acc2[mi][bt]);
        }
      }
      #pragma unroll
      for (int mi=0;mi<4;mi++){
        int mt = mq*4 + mi;
        float4 bb = *(const float4*)(b1v + mt*16 + quad*4);
        #pragma unroll
        for (int bt=0;bt<4;bt++)
          *(bf16x4v*)(R + ((nh*4+bt)*16 + l16)*HSTRIDE + mt*16 + quad*4) =
              relu_cvt4(acc2[mi][bt], bb);
      }
    } else if (doE){
      #pragma unroll
      for (int pp = 0; pp < 2; pp++){
        f32x2 ewh[8];
        f32x2 sum = {0.f, 0.f};
        #pragma unroll
        for (int i=0;i<8;i++){
          f32x2 e;
          e[0] = __builtin_amdgcn_exp2f((float)ev0[pp][i]);
          e[1] = __builtin_amdgcn_exp2f((float)ev1[pp][i]);
          ewh[i] = e; sum += e;
        }
        f32x2 scale;
        scale[0] = 1.9984f * __builtin_amdgcn_rcpf(sum[0]);
        scale[1] = 1.9984f * __builtin_amdgcn_rcpf(sum[1]);
        const f32x2 off2 = {2e-4f, 2e-4f};

        float xv = xv_s[pp];
        bool msk = (xv <= -0.999f) || (xv >= 0.999f);
        float xin = msk ? 0.f : xv;

        f32x2 whi = ewh[0]*scale + off2;
        f32x2 ec; ec[0] = -1.f + whi[0]; ec[1] = -1.f + whi[1];
        f32x2 xyk = {-1.f, -1.f};
        f32x2 whk = whi;
        float zk = ZSENT, zk1 = (float)ev2[pp][0];
        #pragma unroll
        for (int i=1;i<8;i++){
          whi = ewh[i]*scale + off2;
          bool le = (ec[0] <= xin);
          xyk = le ? ec : xyk;
          whk = le ? whi : whk;
          zk  = le ? (float)ev2[pp][i-1] : zk;
          zk1 = le ? ((i==7) ? ZSENT : (float)ev2[pp][i]) : zk1;
          ec += whi;
        }
        xyk_s[pp] = xyk; whk_s[pp] = whk;
        zk_s[pp] = zk; zk1_s[pp] = zk1; msk_s[pp] = msk;
      }
    }
    __syncthreads();   // S2: h2 in R complete

    // ================= S2-S3: G3 reads R, writes raw -> H  ||  E: spline
    if (doW){
      f32x4 acc[4][3];                   // interval-local
      #pragma unroll
      for (int bt=0;bt<4;bt++)
        #pragma unroll
        for (int mi=0;mi<3;mi++) acc[bt][mi] = z4;
      #pragma unroll
      for (int kb=0;kb<8;kb++){
        bf16x8 hf[4];
        #pragma unroll
        for (int bt=0;bt<4;bt++)
          hf[bt] = *(const bf16x8*)(R + ((mh*4+bt)*16 + l16)*HSTRIDE + kb*32 + quad*8);
        #pragma unroll
        for (int mi=0;mi<3;mi++){
          bf16x8 a = *(const bf16x8*)(swWo + ((kb*12 + nc*3 + mi)*64 + lane)*8);
          #pragma unroll
          for (int bt=0;bt<4;bt++)
            acc[bt][mi] = MFMA16(a, hf[bt], acc[bt][mi]);
        }
      }
      #pragma unroll
      for (int mi=0;mi<3;mi++){
        int mt = nc*3 + mi;
        float4 bb = *(const float4*)(boutp + mt*16 + quad*4);
        #pragma unroll
        for (int bt=0;bt<4;bt++){
          int row = (mh*4+bt)*16 + l16;
          *(bf16x4v*)(H + row*HSTRIDE + mt*16 + quad*4) = add_cvt4(acc[bt][mi], bb);
        }
      }
    } else if (doE){
      float ldv[2];
      #pragma unroll
      for (int pp = 0; pp < 2; pp++){
        int p   = tid2 + pp*512;
        int row = p >> 3;
        int t   = p & 7;
        long gr = row0E + row;
        float xv = xv_s[pp];
        bool msk = msk_s[pp];
        float xin = msk ? 0.f : xv;
        f32x2 xyk = xyk_s[pp], whk = whk_s[pp];

        float za = zk_s[pp] + SPCONST, zb = zk1_s[pp] + SPCONST;
        float dk  = (fmaxf(za,0.f) + __builtin_amdgcn_logf(1.f + __builtin_amdgcn_exp2f(-fabsf(za))))*LN2 + 1e-4f;
        float dk1 = (fmaxf(zb,0.f) + __builtin_amdgcn_logf(1.f + __builtin_amdgcn_exp2f(-fabsf(zb))))*LN2 + 1e-4f;

        float rwk = __builtin_amdgcn_rcpf(whk[0]);
        float sk  = whk[1] * rwk;
        float eps = (xin - xyk[0]) * rwk;
        float om  = 1.f - eps;
        float et  = eps * om;
        float e2  = eps * eps;
        float beta  = sk + (dk1 + dk - 2.f*sk) * et;
        float rb    = __builtin_amdgcn_rcpf(beta);
        float alpha = whk[1] * (sk*e2 + dk*et);
        float yv  = msk ? xv : (xyk[1] + alpha * rb);
        float num = dk1*e2 + 2.f*sk*et + dk*om*om;
        float ld  = msk ? 0.f : __builtin_amdgcn_logf(sk*sk*num*rb*rb) * LN2;

        out[gr*16 + t] = yv;
        ldv[pp] = ld;
      }
      float s0 = ldv[0], s1 = ldv[1];
      #pragma unroll
      for (int m = 1; m < 8; m <<= 1){
        s0 += __shfl_xor(s0, m);
        s1 += __shfl_xor(s1, m);
      }
      if ((lane & 7) == 0){
        int r = tid2 >> 3;               // 0..63
        out[(long)nrows*16 + row0E + r]      = s0;
        out[(long)nrows*16 + row0E + r + 64] = s1;
      }
    }
    __syncthreads();   // S3: raw(t) in H complete -> next iter's R
  }
}

extern "C" void kernel_launch(void* const* d_in, const int* in_sizes, int n_in,
                              void* d_out, int out_size, void* d_ws, size_t ws_size,
                              hipStream_t stream)
{
  const float* x    = (const float*)d_in[0];
  const float* W0   = (const float*)d_in[1];
  const float* b0   = (const float*)d_in[2];
  const float* W1   = (const float*)d_in[3];
  const float* b1   = (const float*)d_in[4];
  const float* Wout = (const float*)d_in[5];
  const float* bout = (const float*)d_in[6];
  float* out = (float*)d_out;
  __bf16* sw = (__bf16*)d_ws;

  int nrows  = in_sizes[0] / 16;         // 524288
  int ntiles = nrows / ROWS;             // 4096
  int nblk   = ntiles / IT;              // 256 = 1 block per CU

  prep_kernel<<<(SW_TOTAL + 192 + 255)/256, 256, 0, stream>>>(W0, W1, Wout, bout, sw);
  fused_kernel<<<nblk, 1024, 0, stream>>>(x, b0, b1, sw, out, nrows);
}